// Round 5
// baseline (328.319 us; speedup 1.0000x reference)
//
#include <hip/hip_runtime.h>
#include <hip/hip_bf16.h>

#define BSZ    2
#define LSEQ   4096
#define DMODEL 2048
#define DTR    128
#define DST    16
#define ODIM   160            // DTR + 2*DST
#define MROWS  (BSZ*LSEQ)     // 8192
#define CH     64             // chunks along L
#define TT     (LSEQ/CH)      // 64 steps per chunk
#define STRD   258            // padded LDS row stride (258%32=2 -> <=2-way, free)
#define LOG2E  1.44269504088896340736f
#define LN2    0.69314718055994530942f

typedef short  short8  __attribute__((ext_vector_type(8)));
typedef float  floatx4 __attribute__((ext_vector_type(4)));
typedef float  floatx2 __attribute__((ext_vector_type(2)));

__device__ __forceinline__ unsigned short f2bf(float f) {
    unsigned u = __float_as_uint(f);
    u += 0x7fffu + ((u >> 16) & 1u);      // round-to-nearest-even
    return (unsigned short)(u >> 16);
}
__device__ __forceinline__ float quantv(float x, float s, float inv_s) {
    float q = rintf(x * inv_s);
    q = fminf(fmaxf(q, -128.0f), 127.0f);
    return q * s;
}
__device__ __forceinline__ float softplus_fast(float v) {
    float t = __builtin_amdgcn_exp2f(-fabsf(v) * LOG2E);
    return fmaxf(v, 0.0f) + LN2 * __log2f(1.0f + t);
}
__device__ __forceinline__ float scale_from_bits(unsigned bits) {
    return fmaxf(__uint_as_float(bits) * (1.0f/127.0f), 1e-8f);
}
// packed MFMA-fragment offset for row-major [R x K], 16x16x32 frags
__device__ __forceinline__ int pidx(int r, int k, int K) {
    return (r >> 4)*(16*K) + ((k >> 5) << 9) + (((r & 15) + (((k & 31) >> 3) << 4)) << 3) + (k & 7);
}

// ---------------------------------------------------------------- prep ------
#define PB_WX  160
#define PB_WDT 128
#define PB_A   128
#define PB_D   1
#define PREP_BLOCKS (PB_WX + PB_WDT + PB_A + PB_D)

__global__ __launch_bounds__(256) void k_prep(
    const float* __restrict__ Wx, const float* __restrict__ Wdt,
    const float* __restrict__ A_log, const float* __restrict__ Dskip,
    unsigned short* __restrict__ Wxq, unsigned short* __restrict__ Wdtq,
    float* __restrict__ a2, float* __restrict__ Dq)
{
    int bid = blockIdx.x, tid = threadIdx.x;
    __shared__ float red[256];
    if (bid < PB_WX) {                       // Wx row: per-channel quant -> packed bf16
        int o = bid, base = o * DMODEL;
        float m = 0.0f;
        for (int i = tid; i < DMODEL; i += 256) m = fmaxf(m, fabsf(Wx[base+i]));
        red[tid] = m; __syncthreads();
        for (int s2 = 128; s2 > 0; s2 >>= 1) { if (tid < s2) red[tid] = fmaxf(red[tid], red[tid+s2]); __syncthreads(); }
        float s = fmaxf(red[0]*(1.0f/127.0f), 1e-8f), inv = 1.0f/s;
        for (int i = tid; i < DMODEL; i += 256)
            Wxq[pidx(o, i, DMODEL)] = f2bf(quantv(Wx[base+i], s, inv));
    } else if (bid < PB_WX + PB_WDT) {       // Wdt n-tile: 16 rows, 8 elems/thread
        int n = (bid - PB_WX)*16 + (tid >> 4);
        int k0 = (tid & 15)*8;
        const float* src = Wdt + (size_t)n*DTR + k0;
        float4 v0 = *reinterpret_cast<const float4*>(src);
        float4 v1 = *reinterpret_cast<const float4*>(src + 4);
        float m = fmaxf(fmaxf(fmaxf(fabsf(v0.x), fabsf(v0.y)), fmaxf(fabsf(v0.z), fabsf(v0.w))),
                        fmaxf(fmaxf(fabsf(v1.x), fabsf(v1.y)), fmaxf(fabsf(v1.z), fabsf(v1.w))));
        for (int off = 1; off < 16; off <<= 1) m = fmaxf(m, __shfl_xor(m, off, 16));
        float s = fmaxf(m*(1.0f/127.0f), 1e-8f), inv = 1.0f/s;
        short8 o8;
        o8[0]=(short)f2bf(quantv(v0.x,s,inv)); o8[1]=(short)f2bf(quantv(v0.y,s,inv));
        o8[2]=(short)f2bf(quantv(v0.z,s,inv)); o8[3]=(short)f2bf(quantv(v0.w,s,inv));
        o8[4]=(short)f2bf(quantv(v1.x,s,inv)); o8[5]=(short)f2bf(quantv(v1.y,s,inv));
        o8[6]=(short)f2bf(quantv(v1.z,s,inv)); o8[7]=(short)f2bf(quantv(v1.w,s,inv));
        *reinterpret_cast<short8*>(Wdtq + pidx(n, k0, DTR)) = o8;
    } else if (bid < PB_WX + PB_WDT + PB_A) { // A_log -> a2 = -exp(q)*log2e
        int d = (bid - PB_WX - PB_WDT)*16 + (tid >> 4);
        int n = tid & 15;
        float v = A_log[d*DST + n];
        float m = fabsf(v);
        for (int off = 1; off < 16; off <<= 1) m = fmaxf(m, __shfl_xor(m, off, 16));
        float s = fmaxf(m*(1.0f/127.0f), 1e-8f);
        float q = quantv(v, s, 1.0f/s);
        a2[d*DST + n] = -expf(q) * LOG2E;
    } else {                                  // Dskip per-tensor quant
        float m = 0.0f;
        for (int i = tid; i < DMODEL; i += 256) m = fmaxf(m, fabsf(Dskip[i]));
        red[tid] = m; __syncthreads();
        for (int s2 = 128; s2 > 0; s2 >>= 1) { if (tid < s2) red[tid] = fmaxf(red[tid], red[tid+s2]); __syncthreads(); }
        float s = fmaxf(red[0]*(1.0f/127.0f), 1e-8f), inv = 1.0f/s;
        for (int i = tid; i < DMODEL; i += 256) Dq[i] = quantv(Dskip[i], s, inv);
    }
}

// ---- GEMM1 fused (4 waves = 4 K-chunks, LDS-reduced) + dts-max GEMM --------
// outputs: packed bf16 dt-cols, compact B/C cols, x/B/C/dts maxes
__global__ __launch_bounds__(256) void k_mm1(
    const float* __restrict__ x, const unsigned short* __restrict__ Wxq,
    const unsigned short* __restrict__ Wdtq, const float* __restrict__ bdt,
    const float* __restrict__ prompt,
    unsigned short* __restrict__ xdblbf, float* __restrict__ xbc,
    unsigned* __restrict__ scales)
{
    int tid = threadIdx.x, w = tid >> 6, lane = tid & 63;
    int mrow = lane & 15, quad = lane >> 4;
    int mt = blockIdx.x, m0 = mt*16, k0 = w*512;
    floatx4 acc[10] = {};
    float xmax = 0.0f;
    const float* arow = x + (size_t)(m0 + mrow)*DMODEL + k0 + quad*8;
    for (int kk = 0; kk < 512; kk += 32) {
        const float4* ap = reinterpret_cast<const float4*>(arow + kk);
        float4 a0 = ap[0], a1 = ap[1];
        xmax = fmaxf(xmax, fmaxf(fmaxf(fabsf(a0.x), fabsf(a0.y)), fmaxf(fabsf(a0.z), fabsf(a0.w))));
        xmax = fmaxf(xmax, fmaxf(fmaxf(fabsf(a1.x), fabsf(a1.y)), fmaxf(fabsf(a1.z), fabsf(a1.w))));
        short8 af;
        af[0]=(short)f2bf(a0.x); af[1]=(short)f2bf(a0.y); af[2]=(short)f2bf(a0.z); af[3]=(short)f2bf(a0.w);
        af[4]=(short)f2bf(a1.x); af[5]=(short)f2bf(a1.y); af[6]=(short)f2bf(a1.z); af[7]=(short)f2bf(a1.w);
        int kcidx = (k0 + kk) >> 5;
        #pragma unroll
        for (int j = 0; j < 10; ++j) {
            short8 bf = *reinterpret_cast<const short8*>(Wxq + j*16*DMODEL + kcidx*512 + lane*8);
            acc[j] = __builtin_amdgcn_mfma_f32_16x16x32_bf16(af, bf, acc[j], 0, 0, 0);
        }
    }
    for (int off = 32; off; off >>= 1) xmax = fmaxf(xmax, __shfl_xor(xmax, off, 64));
    __shared__ float red[4*2560];
    __shared__ float redB[256], redC[256];
    __shared__ float wred[4], wd[4];
    __shared__ unsigned short lds_abf[2048];   // this block's bf16 A-tile, packed frag order
    if (lane == 0) wred[w] = xmax;
    #pragma unroll
    for (int j = 0; j < 10; ++j) {
        float4 v = make_float4(acc[j][0], acc[j][1], acc[j][2], acc[j][3]);
        *reinterpret_cast<float4*>(&red[w*2560 + (j*16 + mrow)*16 + quad*4]) = v;
    }
    __syncthreads();
    float bmax = 0.0f, cmax = 0.0f;
    #pragma unroll
    for (int j = 0; j < 10; ++j) {
        int e = j*256 + tid;
        float v = red[e] + red[2560+e] + red[5120+e] + red[7680+e];
        int col = e >> 4, rowin = e & 15, row = m0 + rowin;
        if (col < DTR) {
            int off = ((col>>5)<<9) + ((rowin + (((col&31)>>3)<<4))<<3) + (col&7);
            unsigned short bfb = f2bf(v);
            xdblbf[mt*16*DTR + off] = bfb;
            lds_abf[off] = bfb;
        } else if (col < DTR + DST) {
            bmax = fmaxf(bmax, fabsf(v));
            xbc[(size_t)row*32 + (col - DTR)] = v;
        } else {
            v += prompt[(size_t)row*DST + (col - DTR - DST)];
            cmax = fmaxf(cmax, fabsf(v));
            xbc[(size_t)row*32 + 16 + (col - DTR - DST)] = v;
        }
    }
    redB[tid] = bmax; redC[tid] = cmax; __syncthreads();
    for (int s2 = 128; s2 > 0; s2 >>= 1) {
        if (tid < s2) { redB[tid] = fmaxf(redB[tid], redB[tid+s2]); redC[tid] = fmaxf(redC[tid], redC[tid+s2]); }
        __syncthreads();
    }
    // ---- fused dts-max GEMM: this block's 16 rows x all 2048 n, K=128 ------
    short8 afr[4];
    #pragma unroll
    for (int kc = 0; kc < 4; ++kc)
        afr[kc] = *reinterpret_cast<const short8*>(lds_abf + (kc<<9) + lane*8);
    float dmax = 0.0f;
    for (int jj = 0; jj < 32; ++jj) {
        int ntile = w*32 + jj;
        const unsigned short* bb = Wdtq + (size_t)ntile*16*DTR + lane*8;
        floatx4 acc2 = {};
        #pragma unroll
        for (int kc = 0; kc < 4; ++kc) {
            short8 bf = *reinterpret_cast<const short8*>(bb + (kc<<9));
            acc2 = __builtin_amdgcn_mfma_f32_16x16x32_bf16(afr[kc], bf, acc2, 0, 0, 0);
        }
        float bv = bdt[ntile*16 + mrow];
        #pragma unroll
        for (int r = 0; r < 4; ++r) dmax = fmaxf(dmax, fabsf(acc2[r] + bv));
    }
    for (int off = 32; off; off >>= 1) dmax = fmaxf(dmax, __shfl_xor(dmax, off, 64));
    if (lane == 0) wd[w] = dmax;
    __syncthreads();
    if (tid == 0) {
        atomicMax(&scales[0], __float_as_uint(fmaxf(fmaxf(wred[0], wred[1]), fmaxf(wred[2], wred[3]))));
        atomicMax(&scales[1], __float_as_uint(redB[0]));
        atomicMax(&scales[2], __float_as_uint(redC[0]));
        atomicMax(&scales[3], __float_as_uint(fmaxf(fmaxf(wd[0], wd[1]), fmaxf(wd[2], wd[3]))));
    }
}

// ---------------- scan phase 1: recompute dts tile, quantize x -> u8, scan --
__global__ __launch_bounds__(256) void k_scan1(
    const unsigned short* __restrict__ Ap, const unsigned short* __restrict__ Bp,
    const float* __restrict__ bdt, const float* __restrict__ x,
    const float* __restrict__ xbc, const float* __restrict__ a2,
    const unsigned* __restrict__ scales, unsigned* __restrict__ u8g,
    float* __restrict__ Aprod, float* __restrict__ hfin)
{
    int bid = blockIdx.x, tid = threadIdx.x;
    int w = tid >> 6, lane = tid & 63;
    int mrow = lane & 15, quad = lane >> 4;
    int b = bid >> 9, rem = bid & 511, dblk = rem >> 6, ch = rem & 63;
    int d0 = dblk*256, t0 = ch*TT;
    int d = d0 + tid;
    float s_u  = scale_from_bits(scales[0]), inv_su = 1.0f/s_u;
    float s_B  = scale_from_bits(scales[1]), inv_sB  = 1.0f/s_B;
    float s_dt = scale_from_bits(scales[3]), inv_sdt = 1.0f/s_dt;
    floatx2 a22[8];
    {
        const floatx2* ap = reinterpret_cast<const floatx2*>(a2 + (size_t)d*DST);
        #pragma unroll
        for (int i = 0; i < 8; ++i) a22[i] = ap[i];
    }
    floatx2 h2[8];
    #pragma unroll
    for (int i = 0; i < 8; ++i) h2[i] = (floatx2){0.0f, 0.0f};
    float sdt = 0.0f;
    __shared__ float lds_dts[16*STRD];         // 16.5 KB (padded: no store conflicts)
    __shared__ unsigned lds_u[16*64];          // 4 KB
    __shared__ __align__(16) float Bq_p[16*16];
    for (int st = 0; st < TT/16; ++st) {
        int tb = t0 + st*16;
        // ---- MFMA: dts tile [16 t x 256 d] -> LDS (bit-identical to k_mm1) -
        int gm = (b*LSEQ + tb) >> 4;
        short8 afr[4];
        #pragma unroll
        for (int kc = 0; kc < 4; ++kc)
            afr[kc] = *reinterpret_cast<const short8*>(Ap + (size_t)gm*16*DTR + (kc<<9) + lane*8);
        #pragma unroll
        for (int j = 0; j < 4; ++j) {
            int ntile = dblk*16 + w*4 + j;
            int dloc = w*64 + j*16 + mrow;
            float bdtv = bdt[d0 + dloc];
            floatx4 acc = {};
            #pragma unroll
            for (int kc = 0; kc < 4; ++kc) {
                short8 bf = *reinterpret_cast<const short8*>(Bp + (size_t)ntile*16*DTR + (kc<<9) + lane*8);
                acc = __builtin_amdgcn_mfma_f32_16x16x32_bf16(afr[kc], bf, acc, 0, 0, 0);
            }
            #pragma unroll
            for (int r = 0; r < 4; ++r)
                lds_dts[(quad*4 + r)*STRD + dloc] = acc[r] + bdtv;
        }
        // ---- stage x -> codes (lds + coalesced u8 global) + quantized B ----
        {
            const float4* x4 = reinterpret_cast<const float4*>(x);
            #pragma unroll
            for (int i = 0; i < 4; ++i) {
                int q = i*256 + tid, row = q >> 6, c4 = q & 63;
                size_t gi = (size_t)(b*LSEQ + tb + row)*(DMODEL/4) + dblk*64 + c4;
                float4 v = x4[gi];
                int q0 = (int)fminf(fmaxf(rintf(v.x*inv_su), -128.0f), 127.0f);
                int q1 = (int)fminf(fmaxf(rintf(v.y*inv_su), -128.0f), 127.0f);
                int q2 = (int)fminf(fmaxf(rintf(v.z*inv_su), -128.0f), 127.0f);
                int q3 = (int)fminf(fmaxf(rintf(v.w*inv_su), -128.0f), 127.0f);
                unsigned u = (q0 & 255) | ((q1 & 255) << 8) | ((q2 & 255) << 16) | ((unsigned)(q3 & 255) << 24);
                lds_u[row*64 + c4] = u;
                u8g[gi] = u;
            }
            Bq_p[tid] = quantv(xbc[(size_t)(b*LSEQ + tb + (tid>>4))*32 + (tid&15)], s_B, inv_sB);
        }
        __syncthreads();
        const signed char* lub = reinterpret_cast<const signed char*>(lds_u);
        for (int t = 0; t < 16; ++t) {
            float dtq = quantv(lds_dts[t*STRD + tid], s_dt, inv_sdt);
            float dtv = softplus_fast(dtq);
            float uq  = s_u * (float)lub[t*256 + tid];
            float dtu = dtv * uq;
            sdt += dtv;
            floatx2 dtv2 = {dtv, dtv}, dtu2 = {dtu, dtu};
            const floatx2* bq2 = reinterpret_cast<const floatx2*>(&Bq_p[t*16]);
            #pragma unroll
            for (int n2 = 0; n2 < 8; ++n2) {
                floatx2 e = a22[n2] * dtv2;
                floatx2 dA; dA.x = __builtin_amdgcn_exp2f(e.x); dA.y = __builtin_amdgcn_exp2f(e.y);
                h2[n2] = dA*h2[n2] + bq2[n2]*dtu2;
            }
        }
        __syncthreads();
    }
    size_t ob = ((size_t)((b*CH + ch)*DMODEL + d))*DST;
    floatx2 sdt2 = {sdt, sdt};
    #pragma unroll
    for (int i = 0; i < 4; ++i) {
        floatx2 e0 = a22[2*i] * sdt2, e1 = a22[2*i+1] * sdt2;
        float4 av = make_float4(__builtin_amdgcn_exp2f(e0.x), __builtin_amdgcn_exp2f(e0.y),
                                __builtin_amdgcn_exp2f(e1.x), __builtin_amdgcn_exp2f(e1.y));
        float4 hv = make_float4(h2[2*i].x, h2[2*i].y, h2[2*i+1].x, h2[2*i+1].y);
        *reinterpret_cast<float4*>(Aprod + ob + 4*i) = av;
        *reinterpret_cast<float4*>(hfin  + ob + 4*i) = hv;
    }
}

// ------------------------- scan phase 2: across-chunk recurrence (in-place) -
__global__ __launch_bounds__(256) void k_mid(
    float* __restrict__ Aprod, const float* __restrict__ hfin)
{
    int f = blockIdx.x*256 + threadIdx.x;      // 65536 = B*DMODEL*DST
    int b = f >> 15, dn = f & 32767;
    size_t base = (size_t)b*CH*32768 + dn;
    float h = 0.0f;
    #pragma unroll 4
    for (int ch = 0; ch < CH; ++ch) {
        size_t o = base + (size_t)ch*32768;
        float a = Aprod[o], hf = hfin[o];
        Aprod[o] = h;                          // exclusive prefix -> h_init
        h = fmaf(a, h, hf);
    }
}

// ------------- scan phase 3: recompute dts tile, replay, y + u_q*D_q -> out -
__global__ __launch_bounds__(256) void k_scan3(
    const unsigned short* __restrict__ Ap, const unsigned short* __restrict__ Bp,
    const float* __restrict__ bdt, const unsigned* __restrict__ u8g,
    const float* __restrict__ xbc, const float* __restrict__ a2,
    const float* __restrict__ Dq, const unsigned* __restrict__ scales,
    const float* __restrict__ hinit, float* __restrict__ out)
{
    int bid = blockIdx.x, tid = threadIdx.x;
    int w = tid >> 6, lane = tid & 63;
    int mrow = lane & 15, quad = lane >> 4;
    int b = bid >> 9, rem = bid & 511, dblk = rem >> 6, ch = rem & 63;
    int d0 = dblk*256, t0 = ch*TT;
    int d = d0 + tid;
    float s_u  = scale_from_bits(scales[0]);
    float s_B  = scale_from_bits(scales[1]), inv_sB  = 1.0f/s_B;
    float s_C  = scale_from_bits(scales[2]), inv_sC  = 1.0f/s_C;
    float s_dt = scale_from_bits(scales[3]), inv_sdt = 1.0f/s_dt;
    float dqd = Dq[d];
    floatx2 a22[8];
    {
        const floatx2* ap = reinterpret_cast<const floatx2*>(a2 + (size_t)d*DST);
        #pragma unroll
        for (int i = 0; i < 8; ++i) a22[i] = ap[i];
    }
    size_t ob = ((size_t)((b*CH + ch)*DMODEL + d))*DST;
    floatx2 h2[8];
    #pragma unroll
    for (int i = 0; i < 4; ++i) {
        float4 hv = *reinterpret_cast<const float4*>(hinit + ob + 4*i);
        h2[2*i]   = (floatx2){hv.x, hv.y};
        h2[2*i+1] = (floatx2){hv.z, hv.w};
    }
    __shared__ float lds_dts[16*STRD];
    __shared__ unsigned lds_u[16*64];
    __shared__ __align__(16) float Bq_p[16*16];
    __shared__ __align__(16) float Cq_p[16*16];
    for (int st = 0; st < TT/16; ++st) {
        int tb = t0 + st*16;
        int gm = (b*LSEQ + tb) >> 4;
        short8 afr[4];
        #pragma unroll
        for (int kc = 0; kc < 4; ++kc)
            afr[kc] = *reinterpret_cast<const short8*>(Ap + (size_t)gm*16*DTR + (kc<<9) + lane*8);
        #pragma unroll
        for (int j = 0; j < 4; ++j) {
            int ntile = dblk*16 + w*4 + j;
            int dloc = w*64 + j*16 + mrow;
            float bdtv = bdt[d0 + dloc];
            floatx4 acc = {};
            #pragma unroll
            for (int kc = 0; kc < 4; ++kc) {
                short8 bf = *reinterpret_cast<const short8*>(Bp + (size_t)ntile*16*DTR + (kc<<9) + lane*8);
                acc = __builtin_amdgcn_mfma_f32_16x16x32_bf16(afr[kc], bf, acc, 0, 0, 0);
            }
            #pragma unroll
            for (int r = 0; r < 4; ++r)
                lds_dts[(quad*4 + r)*STRD + dloc] = acc[r] + bdtv;
        }
        {
            #pragma unroll
            for (int i = 0; i < 4; ++i) {
                int q = i*256 + tid, row = q >> 6, c4 = q & 63;
                size_t gi = (size_t)(b*LSEQ + tb + row)*(DMODEL/4) + dblk*64 + c4;
                lds_u[row*64 + c4] = u8g[gi];
            }
            size_t px = (size_t)(b*LSEQ + tb + (tid>>4))*32;
            Bq_p[tid] = quantv(xbc[px + (tid&15)],      s_B, inv_sB);
            Cq_p[tid] = quantv(xbc[px + 16 + (tid&15)], s_C, inv_sC);
        }
        __syncthreads();
        const signed char* lub = reinterpret_cast<const signed char*>(lds_u);
        for (int t = 0; t < 16; ++t) {
            float dtq = quantv(lds_dts[t*STRD + tid], s_dt, inv_sdt);
            float dtv = softplus_fast(dtq);
            float uq  = s_u * (float)lub[t*256 + tid];
            float dtu = dtv * uq;
            floatx2 dtv2 = {dtv, dtv}, dtu2 = {dtu, dtu};
            const floatx2* bq2 = reinterpret_cast<const floatx2*>(&Bq_p[t*16]);
            const floatx2* cq2 = reinterpret_cast<const floatx2*>(&Cq_p[t*16]);
            floatx2 y2 = {0.0f, 0.0f};
            #pragma unroll
            for (int n2 = 0; n2 < 8; ++n2) {
                floatx2 e = a22[n2] * dtv2;
                floatx2 dA; dA.x = __builtin_amdgcn_exp2f(e.x); dA.y = __builtin_amdgcn_exp2f(e.y);
                h2[n2] = dA*h2[n2] + bq2[n2]*dtu2;
                y2 = y2 + h2[n2]*cq2[n2];
            }
            float y = y2.x + y2.y;
            __builtin_nontemporal_store(y + uq * dqd, out + (size_t)(b*LSEQ + tb + t)*DMODEL + d);
        }
        __syncthreads();
    }
}

// ---------------------------------------------------------------------------
extern "C" void kernel_launch(void* const* d_in, const int* in_sizes, int n_in,
                              void* d_out, int out_size, void* d_ws, size_t ws_size,
                              hipStream_t stream)
{
    const float* x      = (const float*)d_in[0];
    const float* prompt = (const float*)d_in[1];
    const float* Wx     = (const float*)d_in[2];
    const float* Wdt    = (const float*)d_in[3];
    const float* bdt    = (const float*)d_in[4];
    const float* A_log  = (const float*)d_in[5];
    const float* Dskip  = (const float*)d_in[6];
    float* out = (float*)d_out;
    char* ws = (char*)d_ws;
    size_t off = 0;
    unsigned* scales       = (unsigned*)(ws + off);        off += 256;
    unsigned short* Wxq    = (unsigned short*)(ws + off);  off += (size_t)ODIM*DMODEL*2;
    unsigned short* Wdtq   = (unsigned short*)(ws + off);  off += (size_t)DMODEL*DTR*2;
    float* a2              = (float*)(ws + off);           off += (size_t)DMODEL*DST*4;
    float* Dq              = (float*)(ws + off);           off += (size_t)DMODEL*4;
    float* xbc             = (float*)(ws + off);           off += (size_t)MROWS*32*4;
    unsigned short* xdblbf = (unsigned short*)(ws + off);  off += (size_t)MROWS*DTR*2;
    unsigned* u8g          = (unsigned*)(ws + off);        off += (size_t)MROWS*DMODEL;
    float* Aprod           = (float*)(ws + off);           off += (size_t)BSZ*CH*DMODEL*DST*4;
    float* hfin            = (float*)(ws + off);           off += (size_t)BSZ*CH*DMODEL*DST*4;

    hipMemsetAsync(scales, 0, 256, stream);
    hipLaunchKernelGGL(k_prep, dim3(PREP_BLOCKS), dim3(256), 0, stream,
                       Wx, Wdt, A_log, Dskip, Wxq, Wdtq, a2, Dq);
    hipLaunchKernelGGL(k_mm1, dim3(MROWS/16), dim3(256), 0, stream,
                       x, Wxq, Wdtq, bdt, prompt, xdblbf, xbc, scales);
    hipLaunchKernelGGL(k_scan1, dim3(BSZ*8*CH), dim3(256), 0, stream,
                       xdblbf, Wdtq, bdt, x, xbc, a2, scales, u8g, Aprod, hfin);
    hipLaunchKernelGGL(k_mid, dim3(BSZ*DMODEL*DST/256), dim3(256), 0, stream,
                       Aprod, hfin);
    hipLaunchKernelGGL(k_scan3, dim3(BSZ*8*CH), dim3(256), 0, stream,
                       xdblbf, Wdtq, bdt, u8g, xbc, a2, Dq, scales, Aprod, out);
}